// Round 13
// baseline (35.079 us; speedup 1.0000x reference)
//
#include <hip/hip_runtime.h>
#include <stdint.h>

#define NPRED   16384
#define NGT     128
#define KSEL    64
#define CAP     256
#define G       2          // gts per block
#define THREADS 512        // 8 waves; 4 blocks/CU -> 32 waves/CU
#define NBLK    (16 * NGT / G)      // 1024 blocks
#define RND     (NPRED / (4 * THREADS))   // 8 pipelined rounds of 4 preds/thread
#define CTARGET 128.0f     // target E[candidates] per gt (5.7 sigma above K=64)

typedef unsigned long long u64;

// Outputs (float32, concatenated): ious[16*128*64], mask[...], k_idx[...]
#define OUT_IOUS 0
#define OUT_MASK (16 * NGT * KSEL)
#define OUT_KIDX (2 * 16 * NGT * KSEL)

// Per-gt adaptive squared radius: solve area(disk(r) ∩ [0,1]^2) = CTARGET/NPRED
// via fixed-point on the separable clip approximation area ≈ pi r^2 fx fy.
// Conservative in partial-clip. Only OUR filter; exactness comes from the key.
__device__ __forceinline__ float adaptive_T2(float x, float y) {
    const float A = CTARGET / (float)NPRED;
    float r = __fsqrt_rn(A * (1.0f / 3.14159265f));
    #pragma unroll
    for (int it = 0; it < 3; ++it) {
        const float inv2r = 0.5f / r;
        float fx = (fminf(x + r, 1.0f) - fmaxf(x - r, 0.0f)) * inv2r;
        float fy = (fminf(y + r, 1.0f) - fmaxf(y - r, 0.0f)) * inv2r;
        fx = fmaxf(fx, 0.5f); fy = fmaxf(fy, 0.5f);
        r = __fsqrt_rn(A / (3.14159265f * fx * fy));
    }
    return r * r;
}

// numpy-exact pairwise sum of 64 per-lane values. Validated bit-exact R2-R12.
__device__ __forceinline__ float npsum64(float v, int lane) {
    const int j = lane & 7;
    float r = __shfl(v, j, 64);                       // a[j]
    #pragma unroll
    for (int k = 1; k < 8; ++k)
        r = __fadd_rn(r, __shfl(v, j + 8 * k, 64));   // += a[j+8k], in order
    const float r0 = __shfl(r, 0, 64), r1 = __shfl(r, 1, 64),
                r2 = __shfl(r, 2, 64), r3 = __shfl(r, 3, 64),
                r4 = __shfl(r, 4, 64), r5 = __shfl(r, 5, 64),
                r6 = __shfl(r, 6, 64), r7 = __shfl(r, 7, 64);
    return __fadd_rn(__fadd_rn(__fadd_rn(r0, r1), __fadd_rn(r2, r3)),
                     __fadd_rn(__fadd_rn(r4, r5), __fadd_rn(r6, r7)));
}

// Wave-aggregated LDS append: ONE atomicAdd per wave-hit-group (not per lane).
// Order within cand[] differs from arrival order — harmless, rank-select
// imposes the (dist,idx) total order.
__device__ __forceinline__ void wave_append(
    bool hit, u64 key, int* cnt, u64* buf, int lane)
{
    const u64 m = __ballot(hit);
    if (m) {                                  // wave-uniform branch
        const int leader = (int)(__ffsll((long long)m) - 1);
        int base = 0;
        if (lane == leader) base = atomicAdd(cnt, __popcll(m));
        base = __shfl(base, leader, 64);
        if (hit) {
            const int pos = base + __popcll(m & ((1ull << lane) - 1ull));
            if (pos < CAP) buf[pos] = key;
        }
    }
}

__global__ __launch_bounds__(THREADS, 8) void atss_fused(
    const float* __restrict__ pred,  // [16][16384][4] cxcywh
    const float* __restrict__ gt,    // [16][128][4]  cxcywh
    float* __restrict__ out)
{
    __shared__ u64 cand[G][CAP];
    __shared__ u64 topk[G][KSEL];
    __shared__ int s_cnt[G];

    const int tid = threadIdx.x;
    // Bijective XCD swizzle (1024 = 8 x 128): each XCD gets 128 consecutive
    // gt-groups = 2 batches = 512 KB pred working set (fits 4 MB L2).
    const int bid  = ((blockIdx.x & 7) << 7) | (blockIdx.x >> 3);
    const int base_task = bid * G;          // 2 consecutive gts, same batch
    const int b    = base_task >> 7;
    // Stagger: co-XCD blocks start the panel at different offsets to spread
    // the co-phased L2 request bursts across the panel.
    const int off  = ((blockIdx.x >> 3) & 7) << 11;

    float gx[G], gy[G], T2[G];
    #pragma unroll
    for (int g = 0; g < G; ++g) {
        gx[g] = gt[(base_task + g) * 4 + 0];
        gy[g] = gt[(base_task + g) * 4 + 1];
        T2[g] = adaptive_T2(gx[g], gy[g]);
    }

    if (tid < G) s_cnt[tid] = 0;
    __syncthreads();

    const float* pb = pred + (size_t)b * NPRED * 4;
    const int w    = tid >> 6;
    const int lane = tid & 63;

    // ---- Phase 1: pipelined shared scan (2 gts/pred, 32 preds/thread).
    // Ping-pong 4-load bursts: next burst issued BEFORE consuming current.
    {
        float2 va[4], vb[4];
        int ia[4], ib[4];
        #pragma unroll
        for (int k = 0; k < 4; ++k) {
            ia[k] = (k * THREADS + tid + off) & (NPRED - 1);
            va[k] = *reinterpret_cast<const float2*>(pb + (size_t)ia[k] * 4);
        }
        #pragma unroll
        for (int r = 0; r < RND; ++r) {
            if (r + 1 < RND) {
                #pragma unroll
                for (int k = 0; k < 4; ++k) {
                    ib[k] = ((r + 1) * 4 * THREADS + k * THREADS + tid + off)
                            & (NPRED - 1);
                    vb[k] = *reinterpret_cast<const float2*>(
                        pb + (size_t)ib[k] * 4);
                }
            }
            __builtin_amdgcn_sched_barrier(0);   // loads before consumes
            #pragma unroll
            for (int k = 0; k < 4; ++k) {
                #pragma unroll
                for (int g = 0; g < G; ++g) {
                    float dx = __fsub_rn(gx[g], va[k].x);
                    float dy = __fsub_rn(gy[g], va[k].y);
                    const bool hit = fmaf(dx, dx, dy * dy) < T2[g];
                    u64 key = 0;
                    if (hit) {
                        // numpy-exact f32 key: sqrt((dx*dx)+(dy*dy)), no FMA
                        float d = __fsqrt_rn(__fadd_rn(__fmul_rn(dx, dx),
                                                       __fmul_rn(dy, dy)));
                        key = ((u64)__float_as_uint(d) << 32)
                            | (unsigned)ia[k];
                    }
                    wave_append(hit, key, &s_cnt[g], cand[g], lane);
                }
            }
            #pragma unroll
            for (int k = 0; k < 4; ++k) { va[k] = vb[k]; ia[k] = ib[k]; }
        }
    }
    __syncthreads();

    // ---- Phase 1b: wave-local retry, waves 0..G-1 only (P ~ 1e-5 per gt) ----
    if (w < G) {
        int C = s_cnt[w];
        float T2w = T2[w];
        for (int attempt = 0; attempt < 8 && (C < KSEL || C > CAP); ++attempt) {
            T2w = (C < KSEL) ? T2w * 2.0f : T2w * 0.5f;
            if (lane == 0) s_cnt[w] = 0;
            asm volatile("s_waitcnt lgkmcnt(0)" ::: "memory");
            __builtin_amdgcn_wave_barrier();
            for (int base = 0; base < NPRED; base += 8 * 64) {   // MLP-8 rescan
                float2 v[8];
                #pragma unroll
                for (int k = 0; k < 8; ++k)
                    v[k] = *reinterpret_cast<const float2*>(
                        pb + (size_t)(base + k * 64 + lane) * 4);
                #pragma unroll
                for (int k = 0; k < 8; ++k) {
                    const int i = base + k * 64 + lane;
                    float dx = __fsub_rn(gx[w], v[k].x);
                    float dy = __fsub_rn(gy[w], v[k].y);
                    const bool hit = fmaf(dx, dx, dy * dy) < T2w;
                    u64 key = 0;
                    if (hit) {
                        float d = __fsqrt_rn(__fadd_rn(__fmul_rn(dx, dx),
                                                       __fmul_rn(dy, dy)));
                        key = ((u64)__float_as_uint(d) << 32) | (unsigned)i;
                    }
                    wave_append(hit, key, &s_cnt[w], cand[w], lane);
                }
            }
            asm volatile("s_waitcnt lgkmcnt(0)" ::: "memory");
            __builtin_amdgcn_wave_barrier();
            C = s_cnt[w];
        }
    }
    __syncthreads();    // publish final cand/s_cnt to all 8 waves

    // ---- Phase 2: rank selection, 4 sub-waves per gt, batch-16 LDS reads ----
    {
        const int g2  = w & (G - 1);    // gt handled by this wave
        const int sub = w >> 1;         // candidate-quarter (0..3)
        int C = s_cnt[g2]; C = C > CAP ? CAP : C;
        for (int ci = sub * 64 + lane; ci < C; ci += 256) {
            const u64 key = cand[g2][ci];
            int r = 0, j = 0;
            for (; j + 16 <= C; j += 16) {
                u64 kk[16];
                #pragma unroll
                for (int t = 0; t < 16; ++t) kk[t] = cand[g2][j + t];
                #pragma unroll
                for (int t = 0; t < 16; ++t) r += (kk[t] < key) ? 1 : 0;
            }
            for (; j < C; ++j) r += (cand[g2][j] < key) ? 1 : 0;
            if (r < KSEL) topk[g2][r] = key;
        }
    }
    __syncthreads();    // publish topk

    if (w >= G) return; // waves G..7 done

    // ---- Phase 3: epilogue, wave w -> gt w, numpy-exact f32 ----
    const int task = base_task + w;
    const float* gtp = gt + task * 4;
    const float gcx = gtp[0], gcy = gtp[1], gw = gtp[2], gh = gtp[3];

    const u64 key = topk[w][lane];
    const int idx = (int)(key & (u64)(NPRED - 1));

    const float gx1 = __fsub_rn(gcx, __fmul_rn(0.5f, gw));
    const float gy1 = __fsub_rn(gcy, __fmul_rn(0.5f, gh));
    const float gx2 = __fadd_rn(gcx, __fmul_rn(0.5f, gw));
    const float gy2 = __fadd_rn(gcy, __fmul_rn(0.5f, gh));

    const float4 kb = *reinterpret_cast<const float4*>(pb + (size_t)idx * 4);
    const float kcx = kb.x, kcy = kb.y;
    float kx1 = __fsub_rn(kb.x, __fmul_rn(0.5f, kb.z));
    float ky1 = __fsub_rn(kb.y, __fmul_rn(0.5f, kb.w));
    float kx2 = __fadd_rn(kb.x, __fmul_rn(0.5f, kb.z));
    float ky2 = __fadd_rn(kb.y, __fmul_rn(0.5f, kb.w));
    float ltx = fmaxf(gx1, kx1), lty = fmaxf(gy1, ky1);
    float rbx = fminf(gx2, kx2), rby = fminf(gy2, ky2);
    float wx = fmaxf(__fsub_rn(rbx, ltx), 0.0f);
    float wy = fmaxf(__fsub_rn(rby, lty), 0.0f);
    float inter = __fmul_rn(wx, wy);
    float ag = __fmul_rn(__fsub_rn(gx2, gx1), __fsub_rn(gy2, gy1));
    float ak = __fmul_rn(__fsub_rn(kx2, kx1), __fsub_rn(ky2, ky1));
    float uni = __fsub_rn(__fadd_rn(ag, ak), inter);
    const float iou = __fdiv_rn(inter, uni);

    const float mean = __fdiv_rn(npsum64(iou, lane), 64.0f);
    const float dd   = __fsub_rn(iou, mean);
    const float var  = __fdiv_rn(npsum64(__fmul_rn(dd, dd), lane), 63.0f);
    const float thr  = __fadd_rn(mean, __fsqrt_rn(var));

    const bool inside = (gx1 <= kcx) && (kcx <= gx2) && (gy1 <= kcy) && (kcy <= gy2);
    const bool m = (iou >= thr) && inside;

    const int o = task * KSEL + lane;
    out[OUT_IOUS + o] = iou;
    out[OUT_MASK + o] = m ? 1.0f : 0.0f;
    out[OUT_KIDX + o] = (float)idx;
}

extern "C" void kernel_launch(void* const* d_in, const int* in_sizes, int n_in,
                              void* d_out, int out_size, void* d_ws, size_t ws_size,
                              hipStream_t stream) {
    const float* pred = (const float*)d_in[0];  // (16,16384,4) f32
    const float* gtb  = (const float*)d_in[1];  // (16,128,4)   f32
    float* out = (float*)d_out;
    hipLaunchKernelGGL(atss_fused, dim3(NBLK), dim3(THREADS), 0, stream,
                       pred, gtb, out);
}

// Round 14
// 27.467 us; speedup vs baseline: 1.2771x; 1.2771x over previous
//
#include <hip/hip_runtime.h>
#include <stdint.h>

#define NPRED   16384
#define NGT     128
#define KSEL    64
#define CAP     256
#define G       2          // gts per block
#define THREADS 512        // 8 waves; 4 blocks/CU -> 32 waves/CU
#define NBLK    (16 * NGT / G)      // 1024 blocks
#define RND     (NPRED / (4 * THREADS))   // 8 rounds of 4 preds/thread
#define CTARGET 128.0f     // target E[candidates] per gt (5.7 sigma above K=64)

typedef unsigned long long u64;

// Outputs (float32, concatenated): ious[16*128*64], mask[...], k_idx[...]
#define OUT_IOUS 0
#define OUT_MASK (16 * NGT * KSEL)
#define OUT_KIDX (2 * 16 * NGT * KSEL)

// Per-gt adaptive squared radius: solve area(disk(r) ∩ [0,1]^2) = CTARGET/NPRED
// via fixed-point on the separable clip approximation area ≈ pi r^2 fx fy.
// Conservative in partial-clip. Only OUR filter; exactness comes from the key.
__device__ __forceinline__ float adaptive_T2(float x, float y) {
    const float A = CTARGET / (float)NPRED;
    float r = __fsqrt_rn(A * (1.0f / 3.14159265f));
    #pragma unroll
    for (int it = 0; it < 3; ++it) {
        const float inv2r = 0.5f / r;
        float fx = (fminf(x + r, 1.0f) - fmaxf(x - r, 0.0f)) * inv2r;
        float fy = (fminf(y + r, 1.0f) - fmaxf(y - r, 0.0f)) * inv2r;
        fx = fmaxf(fx, 0.5f); fy = fmaxf(fy, 0.5f);
        r = __fsqrt_rn(A / (3.14159265f * fx * fy));
    }
    return r * r;
}

// numpy-exact pairwise sum of 64 per-lane values. Validated bit-exact R2-R13.
__device__ __forceinline__ float npsum64(float v, int lane) {
    const int j = lane & 7;
    float r = __shfl(v, j, 64);                       // a[j]
    #pragma unroll
    for (int k = 1; k < 8; ++k)
        r = __fadd_rn(r, __shfl(v, j + 8 * k, 64));   // += a[j+8k], in order
    const float r0 = __shfl(r, 0, 64), r1 = __shfl(r, 1, 64),
                r2 = __shfl(r, 2, 64), r3 = __shfl(r, 3, 64),
                r4 = __shfl(r, 4, 64), r5 = __shfl(r, 5, 64),
                r6 = __shfl(r, 6, 64), r7 = __shfl(r, 7, 64);
    return __fadd_rn(__fadd_rn(__fadd_rn(r0, r1), __fadd_rn(r2, r3)),
                     __fadd_rn(__fadd_rn(r4, r5), __fadd_rn(r6, r7)));
}

__global__ __launch_bounds__(THREADS, 8) void atss_fused(
    const float* __restrict__ pred,  // [16][16384][4] cxcywh
    const float* __restrict__ gt,    // [16][128][4]  cxcywh
    float* __restrict__ out)
{
    __shared__ __align__(16) u64 cand[G][CAP];
    __shared__ u64 topk[G][KSEL];
    __shared__ int s_cnt[G];

    const int tid = threadIdx.x;
    // Bijective XCD swizzle (1024 = 8 x 128): each XCD gets 128 consecutive
    // gt-groups = 2 batches = 512 KB pred working set (fits 4 MB L2).
    const int bid  = ((blockIdx.x & 7) << 7) | (blockIdx.x >> 3);
    const int base_task = bid * G;          // 2 consecutive gts, same batch
    const int b    = base_task >> 7;
    // Stagger: co-XCD blocks start the panel at different offsets to spread
    // the co-phased L2 request bursts across the panel.
    const int off  = ((blockIdx.x >> 3) & 7) << 11;

    float gx[G], gy[G], T2[G];
    #pragma unroll
    for (int g = 0; g < G; ++g) {
        gx[g] = gt[(base_task + g) * 4 + 0];
        gy[g] = gt[(base_task + g) * 4 + 1];
        T2[g] = adaptive_T2(gx[g], gy[g]);
    }

    if (tid < G) s_cnt[tid] = 0;
    __syncthreads();

    const float* pb = pred + (size_t)b * NPRED * 4;
    const int w    = tid >> 6;
    const int lane = tid & 63;

    // ---- Phase 1: pipelined shared scan (2 gts/pred, 32 preds/thread).
    // Depth-2 prefetch: 3 rotating 4-load bursts; bursts issued 2 rounds
    // ahead so 8-12 loads stay in flight continuously. Indices recomputed
    // at consume time (saves VGPRs; keeps 8 waves/SIMD).
    {
        float2 va[4], vb[4], vc[4];
        #pragma unroll
        for (int k = 0; k < 4; ++k) {
            const int i0 = (k * THREADS + tid + off) & (NPRED - 1);
            va[k] = *reinterpret_cast<const float2*>(pb + (size_t)i0 * 4);
        }
        #pragma unroll
        for (int k = 0; k < 4; ++k) {
            const int i1 = (4 * THREADS + k * THREADS + tid + off) & (NPRED - 1);
            vb[k] = *reinterpret_cast<const float2*>(pb + (size_t)i1 * 4);
        }
        #pragma unroll
        for (int r = 0; r < RND; ++r) {
            if (r + 2 < RND) {
                #pragma unroll
                for (int k = 0; k < 4; ++k) {
                    const int i2 = ((r + 2) * 4 * THREADS + k * THREADS + tid
                                    + off) & (NPRED - 1);
                    vc[k] = *reinterpret_cast<const float2*>(
                        pb + (size_t)i2 * 4);
                }
            }
            __builtin_amdgcn_sched_barrier(0);   // loads before consumes
            #pragma unroll
            for (int k = 0; k < 4; ++k) {
                const int i = (r * 4 * THREADS + k * THREADS + tid + off)
                              & (NPRED - 1);
                #pragma unroll
                for (int g = 0; g < G; ++g) {
                    float dx = __fsub_rn(gx[g], va[k].x);
                    float dy = __fsub_rn(gy[g], va[k].y);
                    if (fmaf(dx, dx, dy * dy) < T2[g]) {
                        // numpy-exact f32 key: sqrt((dx*dx)+(dy*dy)), no FMA
                        float d = __fsqrt_rn(__fadd_rn(__fmul_rn(dx, dx),
                                                       __fmul_rn(dy, dy)));
                        int pos = atomicAdd(&s_cnt[g], 1);
                        if (pos < CAP)
                            cand[g][pos] = ((u64)__float_as_uint(d) << 32)
                                         | (unsigned)i;
                    }
                }
            }
            #pragma unroll
            for (int k = 0; k < 4; ++k) { va[k] = vb[k]; vb[k] = vc[k]; }
        }
    }
    __syncthreads();

    // ---- Phase 1b: wave-local retry, waves 0..G-1 only (P ~ 1e-5 per gt) ----
    if (w < G) {
        int C = s_cnt[w];
        float T2w = T2[w];
        for (int attempt = 0; attempt < 8 && (C < KSEL || C > CAP); ++attempt) {
            T2w = (C < KSEL) ? T2w * 2.0f : T2w * 0.5f;
            if (lane == 0) s_cnt[w] = 0;
            asm volatile("s_waitcnt lgkmcnt(0)" ::: "memory");
            __builtin_amdgcn_wave_barrier();
            for (int base = 0; base < NPRED; base += 8 * 64) {   // MLP-8 rescan
                float2 v[8];
                #pragma unroll
                for (int k = 0; k < 8; ++k)
                    v[k] = *reinterpret_cast<const float2*>(
                        pb + (size_t)(base + k * 64 + lane) * 4);
                #pragma unroll
                for (int k = 0; k < 8; ++k) {
                    const int i = base + k * 64 + lane;
                    float dx = __fsub_rn(gx[w], v[k].x);
                    float dy = __fsub_rn(gy[w], v[k].y);
                    if (fmaf(dx, dx, dy * dy) < T2w) {
                        float d = __fsqrt_rn(__fadd_rn(__fmul_rn(dx, dx),
                                                       __fmul_rn(dy, dy)));
                        int pos = atomicAdd(&s_cnt[w], 1);
                        if (pos < CAP)
                            cand[w][pos] =
                                ((u64)__float_as_uint(d) << 32) | (unsigned)i;
                    }
                }
            }
            asm volatile("s_waitcnt lgkmcnt(0)" ::: "memory");
            __builtin_amdgcn_wave_barrier();
            C = s_cnt[w];
        }
    }
    __syncthreads();    // publish final cand/s_cnt to all 8 waves

    // ---- Phase 2: rank selection, 4 sub-waves per gt; 16-key batches read
    // as 8x ds_read_b128 (ulonglong2) to halve LDS instruction count ----
    {
        const int g2  = w & (G - 1);    // gt handled by this wave
        const int sub = w >> 1;         // candidate-quarter (0..3)
        int C = s_cnt[g2]; C = C > CAP ? CAP : C;
        const ulonglong2* c2 = reinterpret_cast<const ulonglong2*>(cand[g2]);
        for (int ci = sub * 64 + lane; ci < C; ci += 256) {
            const u64 key = cand[g2][ci];
            int r = 0, j = 0;
            for (; j + 16 <= C; j += 16) {
                ulonglong2 kk[8];
                #pragma unroll
                for (int t = 0; t < 8; ++t) kk[t] = c2[(j >> 1) + t];
                #pragma unroll
                for (int t = 0; t < 8; ++t)
                    r += (kk[t].x < key) + (kk[t].y < key);
            }
            for (; j < C; ++j) r += (cand[g2][j] < key) ? 1 : 0;
            if (r < KSEL) topk[g2][r] = key;
        }
    }
    __syncthreads();    // publish topk

    if (w >= G) return; // waves G..7 done

    // ---- Phase 3: epilogue, wave w -> gt w, numpy-exact f32 ----
    const int task = base_task + w;
    const float* gtp = gt + task * 4;
    const float gcx = gtp[0], gcy = gtp[1], gw = gtp[2], gh = gtp[3];

    const u64 key = topk[w][lane];
    const int idx = (int)(key & (u64)(NPRED - 1));

    const float gx1 = __fsub_rn(gcx, __fmul_rn(0.5f, gw));
    const float gy1 = __fsub_rn(gcy, __fmul_rn(0.5f, gh));
    const float gx2 = __fadd_rn(gcx, __fmul_rn(0.5f, gw));
    const float gy2 = __fadd_rn(gcy, __fmul_rn(0.5f, gh));

    const float4 kb = *reinterpret_cast<const float4*>(pb + (size_t)idx * 4);
    const float kcx = kb.x, kcy = kb.y;
    float kx1 = __fsub_rn(kb.x, __fmul_rn(0.5f, kb.z));
    float ky1 = __fsub_rn(kb.y, __fmul_rn(0.5f, kb.w));
    float kx2 = __fadd_rn(kb.x, __fmul_rn(0.5f, kb.z));
    float ky2 = __fadd_rn(kb.y, __fmul_rn(0.5f, kb.w));
    float ltx = fmaxf(gx1, kx1), lty = fmaxf(gy1, ky1);
    float rbx = fminf(gx2, kx2), rby = fminf(gy2, ky2);
    float wx = fmaxf(__fsub_rn(rbx, ltx), 0.0f);
    float wy = fmaxf(__fsub_rn(rby, lty), 0.0f);
    float inter = __fmul_rn(wx, wy);
    float ag = __fmul_rn(__fsub_rn(gx2, gx1), __fsub_rn(gy2, gy1));
    float ak = __fmul_rn(__fsub_rn(kx2, kx1), __fsub_rn(ky2, ky1));
    float uni = __fsub_rn(__fadd_rn(ag, ak), inter);
    const float iou = __fdiv_rn(inter, uni);

    const float mean = __fdiv_rn(npsum64(iou, lane), 64.0f);
    const float dd   = __fsub_rn(iou, mean);
    const float var  = __fdiv_rn(npsum64(__fmul_rn(dd, dd), lane), 63.0f);
    const float thr  = __fadd_rn(mean, __fsqrt_rn(var));

    const bool inside = (gx1 <= kcx) && (kcx <= gx2) && (gy1 <= kcy) && (kcy <= gy2);
    const bool m = (iou >= thr) && inside;

    const int o = task * KSEL + lane;
    out[OUT_IOUS + o] = iou;
    out[OUT_MASK + o] = m ? 1.0f : 0.0f;
    out[OUT_KIDX + o] = (float)idx;
}

extern "C" void kernel_launch(void* const* d_in, const int* in_sizes, int n_in,
                              void* d_out, int out_size, void* d_ws, size_t ws_size,
                              hipStream_t stream) {
    const float* pred = (const float*)d_in[0];  // (16,16384,4) f32
    const float* gtb  = (const float*)d_in[1];  // (16,128,4)   f32
    float* out = (float*)d_out;
    hipLaunchKernelGGL(atss_fused, dim3(NBLK), dim3(THREADS), 0, stream,
                       pred, gtb, out);
}